// Round 6
// baseline (7953.755 us; speedup 1.0000x reference)
//
#include <hip/hip_runtime.h>
#include <stdint.h>

// PolicyNetRSNNPB R6: R5 structure + occupancy/latency fixes.
//  - 1024-thread blocks (16 waves/CU, wave = 1 sample): 2x latency hiding.
//  - spike list built ONCE per step (post-rendezvous), reused by layer2(s)
//    and layer1(s+1) (identical mask words).
//  - Wi_s LDS dropped; xw computed from L2 Wi in HALF-chains inside the
//    rendezvous spin window (state-half on even-s, target-half on odd-s;
//    k-ascending fmaf chain preserved -> bit-exact).
//  - LDS 86KB (full 2048-cap lists) -> exactly 1 block/CU -> physical
//    32-blocks/XCD partition stays exact.
//  - spin backoff s_sleep(2)/s_sleep(8) against poll-storm tails.

typedef unsigned long long u64;
typedef unsigned int u32;

#define NB 512
#define HD 2048
#define NSTEPS 128
#define THREADS 1024
#define NBLK 256
#define COLS 256
#define SPB 16
#define NWPS 32
#define LSTN 2688   // 16 lists * 2688 * 2B = 86016 B LDS (cap 2048 + pad -> 1 blk/CU)

#define DMc 0.8187307530779818f
#define DSc 0.6065306597126334f
#define SMc 0.18126924692201818f

// ---- ws layout ----
#define OFF_M1W 0
#define SZ_M1W (2 * NB * NWPS * 8)              // 256 KB (double-buffered m1)
#define OFF_M2H (OFF_M1W + SZ_M1W)
#define SZ_M2H ((size_t)NSTEPS * NB * NWPS * 8) // 16 MB (m2 history)
#define OFF_FLAG (OFF_M2H + SZ_M2H)
#define SZ_FLAG (32 * 32 * 4)                   // flag per group, 128B stride
#define OFF_CNT (OFF_FLAG + SZ_FLAG)            // u32[8] xcd rank counters
#define OFF_DONE (OFF_CNT + 64)                 // u32 done counter

#define HWREG_XCC_ID (20 | ((4 - 1) << 11))     // id=20, offset=0, size=4

__global__ void init_ws(u64* __restrict__ m1W, u32* __restrict__ flags,
                        u32* __restrict__ cnt, u32* __restrict__ done) {
  int i = blockIdx.x * 256 + threadIdx.x;
  if (i < 2 * NB * NWPS) m1W[i] = 0ULL;
  if (i < 32 * 32) flags[i] = 0u;
  if (i < 8) cnt[i] = 0u;
  if (i == 0) *done = 0u;
}

// bit i of low-16 -> bit 4i
__device__ __forceinline__ u64 spread4(u64 x) {
  x &= 0xffffULL;
  x = (x | (x << 24)) & 0x000000FF000000FFULL;
  x = (x | (x << 12)) & 0x000F000F000F000FULL;
  x = (x | (x << 6))  & 0x0303030303030303ULL;
  x = (x | (x << 3))  & 0x1111111111111111ULL;
  return x;
}

__device__ __forceinline__ u64 pack_word(u64 B0, u64 B1, u64 B2, u64 B3, int q) {
  int sh = q * 16;
  return spread4(B0 >> sh) | (spread4(B1 >> sh) << 1) |
         (spread4(B2 >> sh) << 2) | (spread4(B3 >> sh) << 3);
}

// Build ascending spike-index list in LDS from 32 mask words. Returns count.
template <bool ATOMIC>
__device__ __forceinline__ int build_list(const u64* __restrict__ mwords,
                                          uint16_t* __restrict__ lstw, int lane) {
  u64 w = 0ULL;
  if (lane < NWPS) {
    if (ATOMIC)
      w = __hip_atomic_load((u64*)&mwords[lane], __ATOMIC_RELAXED,
                            __HIP_MEMORY_SCOPE_AGENT);
    else
      w = mwords[lane];
  }
  int pc = __popcll(w);
  int pre = pc;
#pragma unroll
  for (int off = 1; off < 64; off <<= 1) {
    int v = __shfl_up(pre, off);
    if (lane >= off) pre += v;
  }
  int excl = pre - pc;
  int total = __shfl(pre, 63);
  int kb = lane << 6;
  while (w) {
    int b = __builtin_ctzll(w);
    w &= w - 1;
    lstw[excl++] = (uint16_t)(kb + b);
  }
  asm volatile("s_waitcnt lgkmcnt(0)" ::: "memory");
  return total;
}

// acc init -> += W rows (ascending k, 8-deep batched) -> LIF update.
__device__ __forceinline__ void gather_lif(const float* __restrict__ Wbase,
                                           const uint16_t* __restrict__ lstw,
                                           int total, const float init0,
                                           const float init1, const float init2,
                                           const float init3, float syn[4],
                                           float mem[4], u32& snib) {
  float a0 = init0, a1 = init1, a2 = init2, a3 = init3;
  for (int j0 = 0; j0 < total; j0 += 8) {
    int got = total - j0;
    got = got > 8 ? 8 : got;
    int kk[8];
    float4 v[8];
#pragma unroll
    for (int u = 0; u < 8; ++u) kk[u] = lstw[j0 + (u < got ? u : 0)];
#pragma unroll
    for (int u = 0; u < 8; ++u)
      v[u] = *(const float4*)(Wbase + ((size_t)kk[u] << 11));
#pragma unroll
    for (int u = 0; u < 8; ++u)
      if (u < got) { a0 += v[u].x; a1 += v[u].y; a2 += v[u].z; a3 += v[u].w; }
  }
  float aj[4] = {a0, a1, a2, a3};
  u32 nib = 0;
#pragma unroll
  for (int j = 0; j < 4; ++j) {
    float so = (float)((snib >> j) & 1u);
    float nmem = (DMc * mem[j] + SMc * syn[j]) * (1.0f - so);  // R1 shape
    float nsyn = DSc * syn[j] + aj[j];                          // R1 shape
    mem[j] = nmem;
    syn[j] = nsyn;
    if ((nmem - 1.0f) > 0.0f) nib |= (1u << j);
  }
  snib = nib;
}

// one 64-k half of the xw chain: xw[j] += x[k] * Wi[k][col], k ascending.
__device__ __forceinline__ void xw_half(const float* __restrict__ xrow,
                                        const float* __restrict__ WiCol,
                                        float xw[4]) {
  for (int q = 0; q < 16; ++q) {
    float4 xq = *(const float4*)(xrow + 4 * q);  // uniform -> broadcast
    float xv[4] = {xq.x, xq.y, xq.z, xq.w};
#pragma unroll
    for (int kj = 0; kj < 4; ++kj) {
      float4 w4 = *(const float4*)(WiCol + (size_t)(4 * q + kj) * HD);
      xw[0] = fmaf(xv[kj], w4.x, xw[0]);
      xw[1] = fmaf(xv[kj], w4.y, xw[1]);
      xw[2] = fmaf(xv[kj], w4.z, xw[2]);
      xw[3] = fmaf(xv[kj], w4.w, xw[3]);
    }
  }
}

__global__ __launch_bounds__(THREADS) void rsnn_coop(
    const float* __restrict__ state, const float* __restrict__ target,
    const float* __restrict__ Wi, const float* __restrict__ bi,
    const float* __restrict__ Vr, const float* __restrict__ Wf,
    const float* __restrict__ bf, const float* __restrict__ Wo,
    const float* __restrict__ bo, float* __restrict__ out,
    char* __restrict__ wsb) {
  __shared__ uint16_t lst[16][LSTN];   // 86 KB -> exactly 1 block/CU
  __shared__ int sh_xcd, sh_rank;

  u64* m1W = (u64*)(wsb + OFF_M1W);
  u64* m2H = (u64*)(wsb + OFF_M2H);
  u32* flags = (u32*)(wsb + OFF_FLAG);
  u32* cnt = (u32*)(wsb + OFF_CNT);
  u32* done = (u32*)(wsb + OFF_DONE);

  const int tid = threadIdx.x;
  const int wv = tid >> 6;      // 0..15, wave = one sample
  const int lane = tid & 63;    // lane = 4 columns

  if (tid == 0) {
    int xcd = __builtin_amdgcn_s_getreg(HWREG_XCC_ID) & 7;
    sh_xcd = xcd;
    sh_rank = atomicAdd(&cnt[xcd], 1u) & 31;
  }
  __syncthreads();
  const int xcd = sh_xcd;
  const int g = sh_rank;
  const int c0 = xcd * COLS;
  const int smp = g * SPB + wv;

  float bir[4], bfr[4];
#pragma unroll
  for (int j = 0; j < 4; ++j) {
    bir[j] = bi[c0 + lane * 4 + j];
    bfr[j] = bf[c0 + lane * 4 + j];
  }

  float syn1[4], mem1[4], syn2[4], mem2[4];
#pragma unroll
  for (int j = 0; j < 4; ++j) { syn1[j] = 0.f; mem1[j] = 0.f; syn2[j] = 0.f; mem2[j] = 0.f; }
  u32 s1nib = 0u, s2nib = 0u;
  float xw[4];

  const float* VrB = Vr + c0 + lane * 4;
  const float* WfB = Wf + c0 + lane * 4;
  const float* WiC = Wi + c0 + lane * 4;
  u32* myflag = &flags[g * 32];

  int totSaved = 0;   // m1(-1) = 0 spikes

  // xw(t=0): full chain before the loop
#pragma unroll
  for (int j = 0; j < 4; ++j) xw[j] = bir[j];
  xw_half(state + (size_t)smp * 64, WiC, xw);
  xw_half(target + (size_t)smp * 64, WiC + (size_t)64 * HD, xw);

  for (int s = 0; s < NSTEPS; ++s) {
    u64* m1cur = m1W + (size_t)(s & 1) * NB * NWPS;

    // ---- layer 1: I1 = xw + s1_prev @ Vr (list saved from prev step) ----
    gather_lif(VrB, &lst[wv][0], totSaved, xw[0], xw[1], xw[2], xw[3],
               syn1, mem1, s1nib);
    {
      u64 B0 = __ballot(s1nib & 1u), B1 = __ballot(s1nib & 2u);
      u64 B2 = __ballot(s1nib & 4u), B3 = __ballot(s1nib & 8u);
      if (lane < 4) {
        u64 wd = pack_word(B0, B1, B2, B3, lane);
        __hip_atomic_store(&m1cur[(size_t)smp * NWPS + 4 * xcd + lane], wd,
                           __ATOMIC_RELAXED, __HIP_MEMORY_SCOPE_AGENT);
      }
    }

    // ---- rendezvous (8 sibling blocks); xw half-chain hides in the window ----
    __syncthreads();   // all waves' mask stores drained (vmcnt 0)
    if (tid == 0)
      __hip_atomic_fetch_add(myflag, 1u, __ATOMIC_RELAXED,
                             __HIP_MEMORY_SCOPE_AGENT);
    {
      int t2 = (s >> 1) + 1;   // xw target time-step
      if (t2 < 64) {
        if ((s & 1) == 0) {
#pragma unroll
          for (int j = 0; j < 4; ++j) xw[j] = bir[j];
          xw_half(state + ((size_t)t2 * NB + smp) * 64, WiC, xw);
        } else {
          xw_half(target + ((size_t)t2 * NB + smp) * 64,
                  WiC + (size_t)64 * HD, xw);
        }
      }
    }
    if (tid == 0) {
      u32 tgt = 8u * (u32)(s + 1);
      while (__hip_atomic_load(myflag, __ATOMIC_RELAXED,
                               __HIP_MEMORY_SCOPE_AGENT) < tgt)
        __builtin_amdgcn_s_sleep(2);
    }
    __syncthreads();

    // ---- build list from m1(s) ONCE: used by layer2 now + layer1 next ----
    totSaved = build_list<true>(m1cur + (size_t)smp * NWPS, &lst[wv][0], lane);

    // ---- layer 2: I2 = bf + ns1 @ Wf ; m2 -> history (sc1, never dirty) ----
    gather_lif(WfB, &lst[wv][0], totSaved, bfr[0], bfr[1], bfr[2], bfr[3],
               syn2, mem2, s2nib);
    {
      u64 B0 = __ballot(s2nib & 1u), B1 = __ballot(s2nib & 2u);
      u64 B2 = __ballot(s2nib & 4u), B3 = __ballot(s2nib & 8u);
      if (lane < 4) {
        u64 wd = pack_word(B0, B1, B2, B3, lane);
        __hip_atomic_store(&m2H[((size_t)s * NB + smp) * NWPS + 4 * xcd + lane],
                           wd, __ATOMIC_RELAXED, __HIP_MEMORY_SCOPE_AGENT);
      }
    }
  }

  // ---- final rendezvous: all m2 history visible to plain loads ----
  __syncthreads();
  if (tid == 0) {
    __threadfence();
    __hip_atomic_fetch_add(done, 1u, __ATOMIC_RELEASE, __HIP_MEMORY_SCOPE_AGENT);
    while (__hip_atomic_load(done, __ATOMIC_RELAXED,
                             __HIP_MEMORY_SCOPE_AGENT) < (u32)NBLK)
      __builtin_amdgcn_s_sleep(8);
    __threadfence();
  }
  __syncthreads();

  // ---- deferred readout: 2 waves/block, wave = one sample ----
  if (wv < 2) {
    const int rsmp = blockIdx.x * 2 + wv;
    const float bor = bo[lane];
    float synr = 0.f, memr = 0.f, roprev = 0.f;
    for (int s = 0; s < NSTEPS; ++s) {
      int total = build_list<false>(m2H + ((size_t)s * NB + rsmp) * NWPS,
                                    &lst[wv][0], lane);
      float a = bor;
      for (int j0 = 0; j0 < total; j0 += 8) {
        int got = total - j0;
        got = got > 8 ? 8 : got;
        int kk[8];
        float vv[8];
#pragma unroll
        for (int u = 0; u < 8; ++u) kk[u] = lst[wv][j0 + (u < got ? u : 0)];
#pragma unroll
        for (int u = 0; u < 8; ++u) vv[u] = Wo[((size_t)kk[u] << 6) + lane];
#pragma unroll
        for (int u = 0; u < 8; ++u)
          if (u < got) a += vv[u];
      }
      float nmemr = DMc * memr + SMc * synr;  // R1 shape
      float nsynr = DSc * synr + a;           // R1 shape
      memr = nmemr;
      synr = nsynr;
      if (s & 1) {
        float v = 0.5f * (roprev + nmemr);
        size_t base = ((size_t)(s >> 1) * NB + rsmp) * 32;
        if (lane < 32) out[base + lane] = v;
        else out[(size_t)64 * NB * 32 + base + (lane - 32)] = v;
      } else {
        roprev = nmemr;
      }
    }
  }
}

extern "C" void kernel_launch(void* const* d_in, const int* in_sizes, int n_in,
                              void* d_out, int out_size, void* d_ws, size_t ws_size,
                              hipStream_t stream) {
  const float* state  = (const float*)d_in[0];
  const float* target = (const float*)d_in[1];
  const float* Wi     = (const float*)d_in[2];
  const float* bi     = (const float*)d_in[3];
  const float* Vr     = (const float*)d_in[4];
  const float* Wf     = (const float*)d_in[5];
  const float* bf     = (const float*)d_in[6];
  const float* Wo     = (const float*)d_in[7];
  const float* bo     = (const float*)d_in[8];
  float* out = (float*)d_out;
  char* wsb = (char*)d_ws;

  init_ws<<<128, 256, 0, stream>>>((u64*)(wsb + OFF_M1W), (u32*)(wsb + OFF_FLAG),
                                   (u32*)(wsb + OFF_CNT), (u32*)(wsb + OFF_DONE));

  void* args[] = {(void*)&state, (void*)&target, (void*)&Wi, (void*)&bi,
                  (void*)&Vr, (void*)&Wf, (void*)&bf, (void*)&Wo, (void*)&bo,
                  (void*)&out, (void*)&wsb};
  hipLaunchCooperativeKernel(rsnn_coop, dim3(NBLK), dim3(THREADS), args, 0, stream);
}